// Round 3
// baseline (160.964 us; speedup 1.0000x reference)
//
#include <hip/hip_runtime.h>
#include <math.h>

// Problem constants (from reference)
#define BATCH 32
#define NGT   50
#define ATOT  10710   // 68*120 + 34*60 + 17*30
#define NCH   16      // 5 + 11 classes
#define L0_END 8160   // 68*120
#define L1_END 10200  // + 34*60
#define APAIR 5355    // ATOT / 2 (each thread handles 2 consecutive anchors)

// Native clang vector types — required by __builtin_nontemporal_load/store
typedef float f32x4 __attribute__((ext_vector_type(4)));
typedef float f32x2 __attribute__((ext_vector_type(2)));

// Pairs of anchors (a0 even) never straddle a row (w ∈ {120,60,30} all even)
// nor a level boundary (8160, 10200, 10710 all even), so x1 = x0+1, same y/s.
__global__ __launch_bounds__(64) void simota_fused_kernel(
    const float* __restrict__ preds,    // (B, A, 16)
    const float* __restrict__ labels,   // (B, G, 5)  [cls, cx, cy, w, h]
    float* __restrict__ out_decoded,    // (B, A, 16)
    float* __restrict__ out_fg,         // (B, A)
    float* __restrict__ out_ibc)        // (B, G, A)
{
    const int b   = blockIdx.y;
    const int tid = threadIdx.x;
    const int pi  = blockIdx.x * 64 + tid;   // pair index

    // Per-g data packed for ds_read_b128: box edges + (gx, gy, validf)
    __shared__ f32x4 s_box[NGT];   // xlo, xhi, ylo, yhi
    __shared__ f32x4 s_ctr[NGT];   // gx, gy, validf, pad
    if (tid < NGT) {
        const float* lr = labels + ((size_t)b * NGT + tid) * 5;
        float l0 = lr[0], gx = lr[1], gy = lr[2], gw = lr[3], gh = lr[4];
        float sum = l0 + gx + gy + gw + gh;       // valid = sum > 0
        float vf  = (sum > 0.0f) ? 1.0f : 0.0f;
        float hw = 0.5f * gw, hh = 0.5f * gh;     // exact
        s_box[tid] = (f32x4){gx - hw, gx + hw, gy - hh, gy + hh};
        s_ctr[tid] = (f32x4){gx, gy, vf, 0.0f};
    }
    __syncthreads();
    if (pi >= APAIR) return;

    const int a0 = 2 * pi;
    int w, la; float s;
    if (a0 < L0_END)      { w = 120; s = 8.0f;  la = a0; }
    else if (a0 < L1_END) { w = 60;  s = 16.0f; la = a0 - L0_END; }
    else                  { w = 30;  s = 32.0f; la = a0 - L1_END; }
    const float xg0 = (float)(la % w);
    const float xg1 = xg0 + 1.0f;
    const float yg  = (float)(la / w);

    // ---- decode 2 anchors (2 × 64 B contiguous per thread) ----
    const float* p = preds + ((size_t)b * ATOT + a0) * NCH;
    f32x4 q[8];
    #pragma unroll
    for (int i = 0; i < 8; ++i)
        q[i] = __builtin_nontemporal_load(((const f32x4*)p) + i);
    q[0].x = (q[0].x + xg0) * s;      // mul by power-of-two stride: exact
    q[0].y = (q[0].y + yg ) * s;
    q[0].z = expf(q[0].z) * s;
    q[0].w = expf(q[0].w) * s;
    q[4].x = (q[4].x + xg1) * s;
    q[4].y = (q[4].y + yg ) * s;
    q[4].z = expf(q[4].z) * s;
    q[4].w = expf(q[4].w) * s;
    f32x4* dptr = (f32x4*)(out_decoded + ((size_t)b * ATOT + a0) * NCH);
    #pragma unroll
    for (int i = 0; i < 8; ++i)
        __builtin_nontemporal_store(q[i], dptr + i);

    // ---- masks for both anchors ----
    const float xc0 = (xg0 + 0.5f) * s;   // exact
    const float xc1 = (xg1 + 0.5f) * s;
    const float yc  = (yg  + 0.5f) * s;
    const float r   = 2.5f * s;           // exact (20/40/80)

    float fg0 = 0.0f, fg1 = 0.0f;
    float* ibc = out_ibc + (size_t)b * NGT * ATOT + a0;
    #pragma unroll 5
    for (int g = 0; g < NGT; ++g) {
        const f32x4 bx = s_box[g];
        const f32x4 cg = s_ctr[g];
        // in_box: min over edge distances (order-invariant min of same values as ref)
        float by = fminf(yc - bx.z, bx.w - yc);
        float b0 = fminf(fminf(xc0 - bx.x, bx.y - xc0), by);
        float b1 = fminf(fminf(xc1 - bx.x, bx.y - xc1), by);
        // in_ctr: center box with per-level radius r (ref rounding: gx-r first)
        float txl = cg.x - r, txh = cg.x + r;
        float tyl = cg.y - r, tyh = cg.y + r;
        float cy = fminf(yc - tyl, tyh - yc);
        float c0 = fminf(fminf(xc0 - txl, txh - xc0), cy);
        float c1 = fminf(fminf(xc1 - txl, txh - xc1), cy);
        const float vf = cg.z;
        // in_box & in_ctr (fg_mask AND is redundant: box∧ctr ⇒ fg)
        float o0 = (fminf(b0, c0) > 0.0f) ? vf : 0.0f;
        float o1 = (fminf(b1, c1) > 0.0f) ? vf : 0.0f;
        // fg accumulator: (in_box | in_ctr) & valid  ==  vf*max(b,c) > 0 (finite)
        fg0 = fmaxf(fg0, vf * fmaxf(b0, c0));
        fg1 = fmaxf(fg1, vf * fmaxf(b1, c1));
        __builtin_nontemporal_store((f32x2){o0, o1},
                                    (f32x2*)(ibc + (size_t)g * ATOT));
    }
    __builtin_nontemporal_store(
        (f32x2){fg0 > 0.0f ? 1.0f : 0.0f, fg1 > 0.0f ? 1.0f : 0.0f},
        (f32x2*)(out_fg + (size_t)b * ATOT + a0));
}

extern "C" void kernel_launch(void* const* d_in, const int* in_sizes, int n_in,
                              void* d_out, int out_size, void* d_ws, size_t ws_size,
                              hipStream_t stream) {
    const float* preds  = (const float*)d_in[0];  // (32, 10710, 16)
    const float* labels = (const float*)d_in[1];  // (32, 50, 5)
    float* out = (float*)d_out;
    // Flat output layout: decoded | fg_mask | in_box_and_ctr
    float* out_decoded = out;
    float* out_fg      = out + (size_t)BATCH * ATOT * NCH;
    float* out_ibc     = out + (size_t)BATCH * ATOT * NCH + (size_t)BATCH * ATOT;

    dim3 grid((APAIR + 63) / 64, BATCH);   // 84 × 32 = 2688 blocks
    dim3 block(64);
    simota_fused_kernel<<<grid, block, 0, stream>>>(preds, labels, out_decoded, out_fg, out_ibc);
}

// Round 4
// 114.600 us; speedup vs baseline: 1.4046x; 1.4046x over previous
//
#include <hip/hip_runtime.h>
#include <math.h>

// Problem constants (from reference)
#define BATCH 32
#define NGT   50
#define ATOT  10710   // 68*120 + 34*60 + 17*30
#define NCH   16      // 5 + 11 classes
#define L0_END 8160   // 68*120
#define L1_END 10200  // + 34*60
#define APAIR 5355    // ATOT / 2 (each thread handles 2 consecutive anchors)

typedef float f32x4 __attribute__((ext_vector_type(4)));
typedef float f32x2 __attribute__((ext_vector_type(2)));

// Pairs of anchors (a0 even) never straddle a row (w ∈ {120,60,30} all even)
// nor a level boundary (8160, 10200, 10710 all even), so x1 = x0+1, same y/s.
// NOTE: plain (cached) loads/stores throughout — nontemporal stores regressed
// WRITE_SIZE 92→128 MB and BW 4x (partial-line writes can't merge in L2).
__global__ __launch_bounds__(256) void simota_fused_kernel(
    const float* __restrict__ preds,    // (B, A, 16)
    const float* __restrict__ labels,   // (B, G, 5)  [cls, cx, cy, w, h]
    float* __restrict__ out_decoded,    // (B, A, 16)
    float* __restrict__ out_fg,         // (B, A)
    float* __restrict__ out_ibc)        // (B, G, A)
{
    const int b   = blockIdx.y;
    const int tid = threadIdx.x;
    const int pi  = blockIdx.x * 256 + tid;   // pair index

    // Per-g data packed for ds_read_b128: box edges + (gx, gy, validf)
    __shared__ f32x4 s_box[NGT];   // xlo, xhi, ylo, yhi
    __shared__ f32x4 s_ctr[NGT];   // gx, gy, validf, pad
    if (tid < NGT) {
        const float* lr = labels + ((size_t)b * NGT + tid) * 5;
        float l0 = lr[0], gx = lr[1], gy = lr[2], gw = lr[3], gh = lr[4];
        float sum = l0 + gx + gy + gw + gh;       // valid = sum > 0
        float vf  = (sum > 0.0f) ? 1.0f : 0.0f;
        float hw = 0.5f * gw, hh = 0.5f * gh;     // exact
        s_box[tid] = (f32x4){gx - hw, gx + hw, gy - hh, gy + hh};
        s_ctr[tid] = (f32x4){gx, gy, vf, 0.0f};
    }
    __syncthreads();
    if (pi >= APAIR) return;

    const int a0 = 2 * pi;
    int w, la; float s;
    if (a0 < L0_END)      { w = 120; s = 8.0f;  la = a0; }
    else if (a0 < L1_END) { w = 60;  s = 16.0f; la = a0 - L0_END; }
    else                  { w = 30;  s = 32.0f; la = a0 - L1_END; }
    const float xg0 = (float)(la % w);
    const float xg1 = xg0 + 1.0f;
    const float yg  = (float)(la / w);

    // ---- decode 2 anchors (2 × 64 B contiguous per thread) ----
    const f32x4* p = (const f32x4*)(preds + ((size_t)b * ATOT + a0) * NCH);
    f32x4 q[8];
    #pragma unroll
    for (int i = 0; i < 8; ++i) q[i] = p[i];
    q[0].x = (q[0].x + xg0) * s;      // mul by power-of-two stride: exact
    q[0].y = (q[0].y + yg ) * s;
    q[0].z = expf(q[0].z) * s;
    q[0].w = expf(q[0].w) * s;
    q[4].x = (q[4].x + xg1) * s;
    q[4].y = (q[4].y + yg ) * s;
    q[4].z = expf(q[4].z) * s;
    q[4].w = expf(q[4].w) * s;
    f32x4* dptr = (f32x4*)(out_decoded + ((size_t)b * ATOT + a0) * NCH);
    #pragma unroll
    for (int i = 0; i < 8; ++i) dptr[i] = q[i];

    // ---- masks for both anchors ----
    const float xc0 = (xg0 + 0.5f) * s;   // exact
    const float xc1 = (xg1 + 0.5f) * s;
    const float yc  = (yg  + 0.5f) * s;
    const float r   = 2.5f * s;           // exact (20/40/80)

    float fg0 = 0.0f, fg1 = 0.0f;
    float* ibc = out_ibc + (size_t)b * NGT * ATOT + a0;
    #pragma unroll 5
    for (int g = 0; g < NGT; ++g) {
        const f32x4 bx = s_box[g];
        const f32x4 cg = s_ctr[g];
        // in_box: min over edge distances (order-invariant min of same values as ref)
        float by = fminf(yc - bx.z, bx.w - yc);
        float b0 = fminf(fminf(xc0 - bx.x, bx.y - xc0), by);
        float b1 = fminf(fminf(xc1 - bx.x, bx.y - xc1), by);
        // in_ctr: center box with per-level radius r
        float txl = cg.x - r, txh = cg.x + r;
        float tyl = cg.y - r, tyh = cg.y + r;
        float cy = fminf(yc - tyl, tyh - yc);
        float c0 = fminf(fminf(xc0 - txl, txh - xc0), cy);
        float c1 = fminf(fminf(xc1 - txl, txh - xc1), cy);
        const float vf = cg.z;
        // in_box & in_ctr (fg_mask AND is redundant: box∧ctr ⇒ fg)
        float o0 = (fminf(b0, c0) > 0.0f) ? vf : 0.0f;
        float o1 = (fminf(b1, c1) > 0.0f) ? vf : 0.0f;
        // fg accumulator: (in_box | in_ctr) & valid  ==  vf*max(b,c) > 0 (finite)
        fg0 = fmaxf(fg0, vf * fmaxf(b0, c0));
        fg1 = fmaxf(fg1, vf * fmaxf(b1, c1));
        *(f32x2*)(ibc + (size_t)g * ATOT) = (f32x2){o0, o1};
    }
    *(f32x2*)(out_fg + (size_t)b * ATOT + a0) =
        (f32x2){fg0 > 0.0f ? 1.0f : 0.0f, fg1 > 0.0f ? 1.0f : 0.0f};
}

extern "C" void kernel_launch(void* const* d_in, const int* in_sizes, int n_in,
                              void* d_out, int out_size, void* d_ws, size_t ws_size,
                              hipStream_t stream) {
    const float* preds  = (const float*)d_in[0];  // (32, 10710, 16)
    const float* labels = (const float*)d_in[1];  // (32, 50, 5)
    float* out = (float*)d_out;
    // Flat output layout: decoded | fg_mask | in_box_and_ctr
    float* out_decoded = out;
    float* out_fg      = out + (size_t)BATCH * ATOT * NCH;
    float* out_ibc     = out + (size_t)BATCH * ATOT * NCH + (size_t)BATCH * ATOT;

    dim3 grid((APAIR + 255) / 256, BATCH);   // 21 × 32 = 672 blocks
    dim3 block(256);
    simota_fused_kernel<<<grid, block, 0, stream>>>(preds, labels, out_decoded, out_fg, out_ibc);
}